// Round 19
// baseline (79.173 us; speedup 1.0000x reference)
//
#include <hip/hip_runtime.h>
#include <hip/hip_bf16.h>
#include <stdint.h>

#define NTOK 8192
#define D_   1024
#define E_   8
#define MT   64
#define NT   128
#define KSTEPS 32     // 16 per expert half, BK=64 bytes
#define MAX_TILES 320
#define BUF_B 12288   // bytes per LDS buffer: A 64*64 + B 128*64

#define LIM_F  0.05412658773652741f      // sqrt(6/(D+D)) exact from shapes
#define SB_F   (LIM_F / 127.0f)
#define INVSB_F (127.0f / LIM_F)

typedef __attribute__((ext_vector_type(4))) int i32x4;

__device__ inline unsigned short f2b(float f) {
    unsigned int u = __float_as_uint(f);
    unsigned int r = (u + 0x7fffu + ((u >> 16) & 1u)) >> 16;
    return (unsigned short)r;
}
__device__ inline int q8(float v, float inv) {
    int q = __float2int_rn(v * inv);
    return max(-127, min(127, q));
}

// async global->LDS, 16B per lane; LDS dest = wave-uniform base + lane*16.
__device__ inline void gload16(const void* g, void* l) {
    __builtin_amdgcn_global_load_lds(
        (const __attribute__((address_space(1))) unsigned int*)(uintptr_t)g,
        (__attribute__((address_space(3))) unsigned int*)(unsigned int)(uintptr_t)l,
        16, 0, 0);
}

// ---- Phase 0+1 fused: gating + i8 cast (blocks 0..2047, 1 token/wave) || We transpose+quant (2048..4095) ----
__global__ __launch_bounds__(256) void prep_kernel(const float* __restrict__ We,
                                                   unsigned char* __restrict__ WeT8,
                                                   const float* __restrict__ x,
                                                   const float* __restrict__ Wg,
                                                   int* __restrict__ g_tok,
                                                   float* __restrict__ wA_tok,
                                                   float* __restrict__ wB_tok,
                                                   float* __restrict__ sA_tok,
                                                   unsigned char* __restrict__ Abf8) {
    __shared__ __align__(16) float smem[8192];   // overlay: 8x1024 wgt | 64x65 tile
    int b = blockIdx.x;
    int t = threadIdx.x;
    if (b < 2048) {
        // ---- gating + per-token amax + i8 cast; 4 tokens/block, ONE token per wave ----
        float* wgt = smem;   // transposed: wgt[e*1024 + d]
        for (int i = t; i < 8192; i += 256) wgt[(i & 7) * 1024 + (i >> 3)] = Wg[i];
        __syncthreads();
        int wave = t >> 6, lane = t & 63;
        int tok = b * 4 + wave;
        const float* xr = x + (size_t)tok * D_;

        float4 xv[4];
        float acc[8] = {0.f, 0.f, 0.f, 0.f, 0.f, 0.f, 0.f, 0.f};
        float ax = 0.f;
        #pragma unroll
        for (int i = 0; i < 4; i++) {
            int d0 = i * 256 + lane * 4;
            xv[i] = *reinterpret_cast<const float4*>(xr + d0);
            ax = fmaxf(ax, fmaxf(fmaxf(fabsf(xv[i].x), fabsf(xv[i].y)),
                                 fmaxf(fabsf(xv[i].z), fabsf(xv[i].w))));
            #pragma unroll
            for (int e = 0; e < 8; e++) {
                float4 w = *reinterpret_cast<const float4*>(&wgt[e * 1024 + d0]);
                acc[e] += xv[i].x * w.x + xv[i].y * w.y + xv[i].z * w.z + xv[i].w * w.w;
            }
        }
        #pragma unroll
        for (int off = 32; off > 0; off >>= 1) ax = fmaxf(ax, __shfl_xor(ax, off, 64));
        #pragma unroll
        for (int e = 0; e < 8; e++)
            #pragma unroll
            for (int off = 32; off > 0; off >>= 1)
                acc[e] += __shfl_xor(acc[e], off, 64);

        float best = acc[0]; int bi = 0;
        #pragma unroll
        for (int e = 1; e < 8; e++) { if (acc[e] > best) { best = acc[e]; bi = e; } }
        float second = -3.4e38f; int si = 0;
        #pragma unroll
        for (int e = 0; e < 8; e++) { if (e != bi && acc[e] > second) { second = acc[e]; si = e; } }
        float eb = __expf(second - best);
        eb = fmaxf(eb, 1e-20f);
        float w0 = 1.f / (1.f + eb);
        float w1 = eb / (1.f + eb);
        int ea, ebx; float wA, wB;
        if (bi < si) { ea = bi; ebx = si; wA = w0; wB = w1; }
        else         { ea = si; ebx = bi; wA = w1; wB = w0; }
        float inv = (ax > 0.f) ? 127.f / ax : 0.f;
        if (lane == 0) {
            g_tok[tok] = ea * 8 + ebx;
            wA_tok[tok] = wA;
            wB_tok[tok] = wB;
            sA_tok[tok] = ax / 127.f;
        }

        unsigned char* rowp = Abf8 + (size_t)tok * D_;
        #pragma unroll
        for (int i = 0; i < 4; i++) {
            int d0 = i * 256 + lane * 4;
            int q0 = q8(xv[i].x, inv), q1 = q8(xv[i].y, inv);
            int q2 = q8(xv[i].z, inv), q3 = q8(xv[i].w, inv);
            unsigned p = (q0 & 0xff) | ((q1 & 0xff) << 8) | ((q2 & 0xff) << 16) | ((q3 & 0xff) << 24);
            *reinterpret_cast<unsigned*>(rowp + d0) = p;
        }
    } else {
        // ---- We (E,D,D) f32 -> WeT8 (E,M,D) int8, constant scale SB ----
        float (*tile)[65] = reinterpret_cast<float (*)[65]>(smem);
        int bb = b - 2048;
        int e = bb >> 8, rem = bb & 255;
        int m0 = (rem & 15) * 64, d0 = (rem >> 4) * 64;
        const float* src = We + ((size_t)e << 20);
        int r = t >> 4, c4 = (t & 15) * 4;
        #pragma unroll
        for (int i = 0; i < 4; i++) {
            int d = r + i * 16;
            float4 v = *reinterpret_cast<const float4*>(src + (size_t)(d0 + d) * D_ + m0 + c4);
            tile[d][c4 + 0] = v.x; tile[d][c4 + 1] = v.y;
            tile[d][c4 + 2] = v.z; tile[d][c4 + 3] = v.w;
        }
        __syncthreads();
        int m = t >> 2, dq = (t & 3) * 16;
        unsigned pk[4];
        #pragma unroll
        for (int jq = 0; jq < 4; jq++) {
            int q0 = q8(tile[dq + jq * 4 + 0][m], INVSB_F);
            int q1 = q8(tile[dq + jq * 4 + 1][m], INVSB_F);
            int q2 = q8(tile[dq + jq * 4 + 2][m], INVSB_F);
            int q3 = q8(tile[dq + jq * 4 + 3][m], INVSB_F);
            pk[jq] = (q0 & 0xff) | ((q1 & 0xff) << 8) | ((q2 & 0xff) << 16) | ((q3 & 0xff) << 24);
        }
        *reinterpret_cast<uint4*>(WeT8 + ((size_t)e << 20) + (size_t)(m0 + m) * D_ + d0 + dq) =
            make_uint4(pk[0], pk[1], pk[2], pk[3]);
    }
}

// ---------------- Phase 2: routing — 64 parallel blocks, uniform 64-row tiles ----------------
__global__ __launch_bounds__(256) void route_kernel(const int* __restrict__ g_tok,
                                                    const float* __restrict__ wA_tok,
                                                    const float* __restrict__ wB_tok,
                                                    const float* __restrict__ sA_tok,
                                                    int* __restrict__ token_list,
                                                    float* __restrict__ wA_s,
                                                    float* __restrict__ wB_s,
                                                    float* __restrict__ sA_s,
                                                    int4* __restrict__ tile_desc,
                                                    int* __restrict__ n_tiles_out) {
    int g = blockIdx.x;    // 0..63
    int t = threadIdx.x;   // 0..255
    __shared__ int cnt[64];
    __shared__ int pfx[256];
    __shared__ int startg, tbase, tottiles;
    if (t < 64) cnt[t] = 0;
    __syncthreads();

    int base = t * 32;
    int gl[32];
    int my = 0;
    #pragma unroll
    for (int k = 0; k < 32; k++) {
        gl[k] = g_tok[base + k];
        my += (gl[k] == g);
    }
    #pragma unroll
    for (int k = 0; k < 32; k++) atomicAdd(&cnt[gl[k]], 1);
    pfx[t] = my;
    __syncthreads();

    if (t == 0) {
        int run = 0, tb = 0, tt = 0;
        for (int gg = 0; gg < 64; gg++) {
            int c = cnt[gg];
            int n = (c + MT - 1) / MT;
            if (gg < g) { run += c; tb += n; }
            tt += n;
        }
        startg = run; tbase = tb; tottiles = tt;
    }
    for (int off = 1; off < 256; off <<= 1) {
        int add = (t >= off) ? pfx[t - off] : 0;
        __syncthreads();
        pfx[t] += add;
        __syncthreads();
    }

    int pos = startg + pfx[t] - my;
    #pragma unroll
    for (int k = 0; k < 32; k++) {
        if (gl[k] == g) {
            int idx = base + k;
            token_list[pos] = idx;
            wA_s[pos] = wA_tok[idx];
            wB_s[pos] = wB_tok[idx];
            sA_s[pos] = sA_tok[idx];
            pos++;
        }
    }
    if (t == 0) {
        int rem = cnt[g], off2 = 0, ti = tbase;
        while (rem > 0) {
            int take = (rem < MT) ? rem : MT;
            tile_desc[ti++] = make_int4(startg + off2, take, g >> 3, g & 7);
            off2 += take; rem -= take;
        }
        if (g == 0) *n_tiles_out = tottiles;
    }
}

// ---------------- Phase 3: grouped GEMM — int8, 64x128 tiles, dbuf + counted vmcnt (R18-frozen) ----------------
__global__ __launch_bounds__(256, 4) void moe_gemm(const unsigned char* __restrict__ Abf8,
                                                   const unsigned char* __restrict__ WeT8,
                                                   const int* __restrict__ token_list,
                                                   const float* __restrict__ wA_s,
                                                   const float* __restrict__ wB_s,
                                                   const float* __restrict__ sA_s,
                                                   const int4* __restrict__ tile_desc,
                                                   const int* __restrict__ n_tiles,
                                                   float* __restrict__ out) {
    int tile = blockIdx.y;
    if (tile >= *n_tiles) return;
    int4 dsc = tile_desc[tile];
    int loff = dsc.x, rows = dsc.y, ea = dsc.z, ebx = dsc.w;
    int ncol0 = blockIdx.x * NT;

    __shared__ __align__(16) unsigned char lds[2 * BUF_B];  // 24 KB: [buf][A 4K | B 8K]
    __shared__ int tokOut[MT];
    __shared__ int tokStage[MT];
    __shared__ float c1sh[MT], c2sh[MT];

    int t = threadIdx.x;
    int wave = t >> 6, lane = t & 63;

    if (t < MT) {
        int idx = loff + ((t < rows) ? t : 0);
        int tk = token_list[idx];
        tokStage[t] = tk;
        tokOut[t] = (t < rows) ? tk : -1;
        float s = sA_s[idx] * SB_F;
        c1sh[t] = s * wA_s[idx];
        c2sh[t] = s * wB_s[idx];
    }
    __syncthreads();

    const unsigned char* wbase = WeT8 + ((size_t)ea << 20);
    size_t ebd = ((size_t)(ebx - ea)) << 20;
    int l15 = lane & 15, hi = lane >> 4, q4 = hi * 4;

    const unsigned char* asrc;
    {
        int row = t >> 2;
        int lc = (t & 3) ^ ((row >> 1) & 3);
        asrc = Abf8 + (size_t)tokStage[row] * D_ + lc * 16;
    }
    const unsigned char* bsrc[2];
    #pragma unroll
    for (int i = 0; i < 2; i++) {
        int c = i * 256 + t;
        int row = c >> 2;
        int lc = (c & 3) ^ ((row >> 1) & 3);
        bsrc[i] = wbase + (size_t)(ncol0 + row) * D_ + lc * 16;
    }

    auto stage = [&](int ks, int buf) {
        int kb = (ks & 15) * 64;
        size_t bo = (size_t)kb + ((ks < 16) ? 0 : ebd);
        unsigned char* base = &lds[buf * BUF_B];
        gload16(asrc + kb, base + wave * 1024);
        #pragma unroll
        for (int i = 0; i < 2; i++)
            gload16(bsrc[i] + bo, base + 4096 + (i * 256 + wave * 64) * 16);
    };

    int wm = (wave >> 1) * 32, wn = (wave & 1) * 64;
    int aoff[2], boff[4];
    #pragma unroll
    for (int m = 0; m < 2; m++) {
        int r = wm + m * 16 + l15;
        aoff[m] = r * 64 + ((hi ^ ((r >> 1) & 3)) << 4);
    }
    #pragma unroll
    for (int n = 0; n < 4; n++) {
        int rb = wn + n * 16 + l15;
        boff[n] = 4096 + rb * 64 + ((hi ^ ((rb >> 1) & 3)) << 4);
    }

    i32x4 acc[2][4];
    unsigned pk[2][4][2];
    #pragma unroll
    for (int m = 0; m < 2; m++)
        #pragma unroll
        for (int n = 0; n < 4; n++) acc[m][n] = (i32x4){0, 0, 0, 0};

    stage(0, 0);
    for (int ks = 0; ks < KSTEPS; ++ks) {
        if (ks < KSTEPS - 1) {
            stage(ks + 1, (ks + 1) & 1);
            asm volatile("s_waitcnt vmcnt(3)" ::: "memory");
        } else {
            asm volatile("s_waitcnt vmcnt(0)" ::: "memory");
        }
        __builtin_amdgcn_s_barrier();
        if (ks == 16) {
            #pragma unroll
            for (int m = 0; m < 2; m++) {
                #pragma unroll
                for (int n = 0; n < 4; n++) {
                    float f0 = (float)acc[m][n][0] * c1sh[wm + m * 16 + q4 + 0];
                    float f1 = (float)acc[m][n][1] * c1sh[wm + m * 16 + q4 + 1];
                    float f2 = (float)acc[m][n][2] * c1sh[wm + m * 16 + q4 + 2];
                    float f3 = (float)acc[m][n][3] * c1sh[wm + m * 16 + q4 + 3];
                    pk[m][n][0] = (unsigned)f2b(f0) | ((unsigned)f2b(f1) << 16);
                    pk[m][n][1] = (unsigned)f2b(f2) | ((unsigned)f2b(f3) << 16);
                    acc[m][n] = (i32x4){0, 0, 0, 0};
                }
            }
        }
        const unsigned char* Ab = &lds[(ks & 1) * BUF_B];
        i32x4 a[2], bfr[4];
        #pragma unroll
        for (int m = 0; m < 2; m++)
            a[m] = *reinterpret_cast<const i32x4*>(&Ab[aoff[m]]);
        #pragma unroll
        for (int n = 0; n < 4; n++)
            bfr[n] = *reinterpret_cast<const i32x4*>(&Ab[boff[n]]);
        #pragma unroll
        for (int m = 0; m < 2; m++)
            #pragma unroll
            for (int n = 0; n < 4; n++)
                acc[m][n] = __builtin_amdgcn_mfma_i32_16x16x64_i8(a[m], bfr[n], acc[m][n], 0, 0, 0);
        __builtin_amdgcn_s_barrier();
    }

    #pragma unroll
    for (int m = 0; m < 2; m++) {
        #pragma unroll
        for (int n = 0; n < 4; n++) {
            int col = ncol0 + wn + n * 16 + l15;
            #pragma unroll
            for (int j = 0; j < 4; j++) {
                int r = wm + m * 16 + q4 + j;
                int tk = tokOut[r];
                unsigned u = pk[m][n][j >> 1];
                float part = __uint_as_float((j & 1) ? (u & 0xffff0000u) : (u << 16));
                if (tk >= 0) out[(size_t)tk * D_ + col] = part + (float)acc[m][n][j] * c2sh[r];
            }
        }
    }
}

extern "C" void kernel_launch(void* const* d_in, const int* in_sizes, int n_in,
                              void* d_out, int out_size, void* d_ws, size_t ws_size,
                              hipStream_t stream) {
    const float* x  = (const float*)d_in[0];
    const float* Wg = (const float*)d_in[1];
    const float* We = (const float*)d_in[2];
    float* out = (float*)d_out;

    size_t off = 0;
    auto alloc = [&](size_t bytes) -> void* {
        void* p = (char*)d_ws + off;
        off += (bytes + 255) & ~(size_t)255;
        return p;
    };
    unsigned char* WeT8 = (unsigned char*)alloc((size_t)E_ * 1024 * 1024);  // 8 MB
    unsigned char* Abf8 = (unsigned char*)alloc((size_t)NTOK * D_);         // 8.4 MB
    int*   g_tok      = (int*)  alloc(NTOK * 4);
    float* wA_tok     = (float*)alloc(NTOK * 4);
    float* wB_tok     = (float*)alloc(NTOK * 4);
    float* sA_tok     = (float*)alloc(NTOK * 4);
    int*   token_list = (int*)  alloc(NTOK * 4);
    float* wA_s       = (float*)alloc(NTOK * 4);
    float* wB_s       = (float*)alloc(NTOK * 4);
    float* sA_s       = (float*)alloc(NTOK * 4);
    int4*  tile_desc  = (int4*) alloc(MAX_TILES * 16);
    int*   n_tiles    = (int*)  alloc(4);

    prep_kernel<<<2048 + 2048, 256, 0, stream>>>(We, WeT8, x, Wg, g_tok, wA_tok, wB_tok,
                                                 sA_tok, Abf8);
    route_kernel<<<64, 256, 0, stream>>>(g_tok, wA_tok, wB_tok, sA_tok,
                                         token_list, wA_s, wB_s, sA_s, tile_desc, n_tiles);
    moe_gemm<<<dim3(8, MAX_TILES), 256, 0, stream>>>(Abf8, WeT8, token_list, wA_s, wB_s, sA_s,
                                                     tile_desc, n_tiles, out);
}

// Round 20
// 74.702 us; speedup vs baseline: 1.0598x; 1.0598x over previous
//
#include <hip/hip_runtime.h>
#include <hip/hip_bf16.h>
#include <stdint.h>

#define NTOK 8192
#define D_   1024
#define E_   8
#define MT   64
#define NT   128
#define KSTEPS 32     // 16 per expert half, BK=64 bytes
#define MAX_TILES 320
#define BUF_B 12288   // bytes per LDS buffer: A 64*64 + B 128*64

#define LIM_F  0.05412658773652741f      // sqrt(6/(D+D)) exact from shapes
#define SB_F   (LIM_F / 127.0f)
#define INVSB_F (127.0f / LIM_F)

typedef __attribute__((ext_vector_type(4))) int i32x4;

__device__ inline unsigned short f2b(float f) {
    unsigned int u = __float_as_uint(f);
    unsigned int r = (u + 0x7fffu + ((u >> 16) & 1u)) >> 16;
    return (unsigned short)r;
}
__device__ inline int q8(float v, float inv) {
    int q = __float2int_rn(v * inv);
    return max(-127, min(127, q));
}

// async global->LDS, 16B per lane; LDS dest = wave-uniform base + lane*16.
__device__ inline void gload16(const void* g, void* l) {
    __builtin_amdgcn_global_load_lds(
        (const __attribute__((address_space(1))) unsigned int*)(uintptr_t)g,
        (__attribute__((address_space(3))) unsigned int*)(unsigned int)(uintptr_t)l,
        16, 0, 0);
}

// ---- Phase 0+1 fused: gating + i8 cast (blocks 0..1023, R18 form) || We transpose+quant (1024..3071) ----
__global__ __launch_bounds__(256) void prep_kernel(const float* __restrict__ We,
                                                   unsigned char* __restrict__ WeT8,
                                                   const float* __restrict__ x,
                                                   const float* __restrict__ Wg,
                                                   int* __restrict__ g_tok,
                                                   float* __restrict__ wA_tok,
                                                   float* __restrict__ wB_tok,
                                                   float* __restrict__ sA_tok,
                                                   unsigned char* __restrict__ Abf8) {
    __shared__ __align__(16) float smem[8192];   // overlay: 8x1024 wgt | 64x65 tile
    int b = blockIdx.x;
    int t = threadIdx.x;
    if (b < 1024) {
        // ---- gating + per-token amax + i8 cast; 8 tokens/block, 2 per wave ----
        float* wgt = smem;   // transposed: wgt[e*1024 + d]
        for (int i = t; i < 8192; i += 256) wgt[(i & 7) * 1024 + (i >> 3)] = Wg[i];
        __syncthreads();
        int wave = t >> 6, lane = t & 63;
        int tok0 = b * 8 + wave * 2;

        for (int tki = 0; tki < 2; tki++) {
            int tok = tok0 + tki;
            const float* xr = x + (size_t)tok * D_;

            float4 xv[4];
            float acc[8] = {0.f, 0.f, 0.f, 0.f, 0.f, 0.f, 0.f, 0.f};
            float ax = 0.f;
            #pragma unroll
            for (int i = 0; i < 4; i++) {
                int d0 = i * 256 + lane * 4;
                xv[i] = *reinterpret_cast<const float4*>(xr + d0);
                ax = fmaxf(ax, fmaxf(fmaxf(fabsf(xv[i].x), fabsf(xv[i].y)),
                                     fmaxf(fabsf(xv[i].z), fabsf(xv[i].w))));
                #pragma unroll
                for (int e = 0; e < 8; e++) {
                    float4 w = *reinterpret_cast<const float4*>(&wgt[e * 1024 + d0]);
                    acc[e] += xv[i].x * w.x + xv[i].y * w.y + xv[i].z * w.z + xv[i].w * w.w;
                }
            }
            #pragma unroll
            for (int off = 32; off > 0; off >>= 1) ax = fmaxf(ax, __shfl_xor(ax, off, 64));
            #pragma unroll
            for (int e = 0; e < 8; e++)
                #pragma unroll
                for (int off = 32; off > 0; off >>= 1)
                    acc[e] += __shfl_xor(acc[e], off, 64);

            float best = acc[0]; int bi = 0;
            #pragma unroll
            for (int e = 1; e < 8; e++) { if (acc[e] > best) { best = acc[e]; bi = e; } }
            float second = -3.4e38f; int si = 0;
            #pragma unroll
            for (int e = 0; e < 8; e++) { if (e != bi && acc[e] > second) { second = acc[e]; si = e; } }
            float eb = __expf(second - best);
            eb = fmaxf(eb, 1e-20f);
            float w0 = 1.f / (1.f + eb);
            float w1 = eb / (1.f + eb);
            int ea, ebx; float wA, wB;
            if (bi < si) { ea = bi; ebx = si; wA = w0; wB = w1; }
            else         { ea = si; ebx = bi; wA = w1; wB = w0; }
            float inv = (ax > 0.f) ? 127.f / ax : 0.f;
            if (lane == 0) {
                g_tok[tok] = ea * 8 + ebx;
                wA_tok[tok] = wA;
                wB_tok[tok] = wB;
                sA_tok[tok] = ax / 127.f;
            }

            unsigned char* rowp = Abf8 + (size_t)tok * D_;
            #pragma unroll
            for (int i = 0; i < 4; i++) {
                int d0 = i * 256 + lane * 4;
                int q0 = q8(xv[i].x, inv), q1 = q8(xv[i].y, inv);
                int q2 = q8(xv[i].z, inv), q3 = q8(xv[i].w, inv);
                unsigned p = (q0 & 0xff) | ((q1 & 0xff) << 8) | ((q2 & 0xff) << 16) | ((q3 & 0xff) << 24);
                *reinterpret_cast<unsigned*>(rowp + d0) = p;
            }
        }
    } else {
        // ---- We (E,D,D) f32 -> WeT8 (E,M,D) int8, constant scale SB ----
        float (*tile)[65] = reinterpret_cast<float (*)[65]>(smem);
        int bb = b - 1024;
        int e = bb >> 8, rem = bb & 255;
        int m0 = (rem & 15) * 64, d0 = (rem >> 4) * 64;
        const float* src = We + ((size_t)e << 20);
        int r = t >> 4, c4 = (t & 15) * 4;
        #pragma unroll
        for (int i = 0; i < 4; i++) {
            int d = r + i * 16;
            float4 v = *reinterpret_cast<const float4*>(src + (size_t)(d0 + d) * D_ + m0 + c4);
            tile[d][c4 + 0] = v.x; tile[d][c4 + 1] = v.y;
            tile[d][c4 + 2] = v.z; tile[d][c4 + 3] = v.w;
        }
        __syncthreads();
        int m = t >> 2, dq = (t & 3) * 16;
        unsigned pk[4];
        #pragma unroll
        for (int jq = 0; jq < 4; jq++) {
            int q0 = q8(tile[dq + jq * 4 + 0][m], INVSB_F);
            int q1 = q8(tile[dq + jq * 4 + 1][m], INVSB_F);
            int q2 = q8(tile[dq + jq * 4 + 2][m], INVSB_F);
            int q3 = q8(tile[dq + jq * 4 + 3][m], INVSB_F);
            pk[jq] = (q0 & 0xff) | ((q1 & 0xff) << 8) | ((q2 & 0xff) << 16) | ((q3 & 0xff) << 24);
        }
        *reinterpret_cast<uint4*>(WeT8 + ((size_t)e << 20) + (size_t)(m0 + m) * D_ + d0 + dq) =
            make_uint4(pk[0], pk[1], pk[2], pk[3]);
    }
}

// ---------------- Phase 2: routing — 64 parallel blocks, uniform 64-row tiles ----------------
__global__ __launch_bounds__(256) void route_kernel(const int* __restrict__ g_tok,
                                                    const float* __restrict__ wA_tok,
                                                    const float* __restrict__ wB_tok,
                                                    const float* __restrict__ sA_tok,
                                                    int* __restrict__ token_list,
                                                    float* __restrict__ wA_s,
                                                    float* __restrict__ wB_s,
                                                    float* __restrict__ sA_s,
                                                    int4* __restrict__ tile_desc,
                                                    int* __restrict__ n_tiles_out) {
    int g = blockIdx.x;    // 0..63
    int t = threadIdx.x;   // 0..255
    __shared__ int cnt[64];
    __shared__ int pfx[256];
    __shared__ int startg, tbase, tottiles;
    if (t < 64) cnt[t] = 0;
    __syncthreads();

    int base = t * 32;
    int gl[32];
    int my = 0;
    #pragma unroll
    for (int k = 0; k < 32; k++) {
        gl[k] = g_tok[base + k];
        my += (gl[k] == g);
    }
    #pragma unroll
    for (int k = 0; k < 32; k++) atomicAdd(&cnt[gl[k]], 1);
    pfx[t] = my;
    __syncthreads();

    if (t == 0) {
        int run = 0, tb = 0, tt = 0;
        for (int gg = 0; gg < 64; gg++) {
            int c = cnt[gg];
            int n = (c + MT - 1) / MT;
            if (gg < g) { run += c; tb += n; }
            tt += n;
        }
        startg = run; tbase = tb; tottiles = tt;
    }
    for (int off = 1; off < 256; off <<= 1) {
        int add = (t >= off) ? pfx[t - off] : 0;
        __syncthreads();
        pfx[t] += add;
        __syncthreads();
    }

    int pos = startg + pfx[t] - my;
    #pragma unroll
    for (int k = 0; k < 32; k++) {
        if (gl[k] == g) {
            int idx = base + k;
            token_list[pos] = idx;
            wA_s[pos] = wA_tok[idx];
            wB_s[pos] = wB_tok[idx];
            sA_s[pos] = sA_tok[idx];
            pos++;
        }
    }
    if (t == 0) {
        int rem = cnt[g], off2 = 0, ti = tbase;
        while (rem > 0) {
            int take = (rem < MT) ? rem : MT;
            tile_desc[ti++] = make_int4(startg + off2, take, g >> 3, g & 7);
            off2 += take; rem -= take;
        }
        if (g == 0) *n_tiles_out = tottiles;
    }
}

// ---------------- Phase 3: grouped GEMM — int8, 64x128 tiles, 2-D XCD affinity ----------------
// 1-D grid b = x8 + 8k, x8 = XCD = 2*colpair + tileparity:
//   colblk = 2*(x8>>1) + (k&1), tile = 2*(k>>1) + (x8&1).
// Per-XCD B slice = 2 colblks = 2 MB (L2-fits, R17-verified); each tile's A read by only
// 4 XCDs (A-fetch 67->34 MB); block count unchanged (~2176, R18's concurrency regime).
// Inner loop R18-frozen: dbuf + counted vmcnt(3); i32 acc -> bf16-packed partial at expert switch.
__global__ __launch_bounds__(256, 4) void moe_gemm(const unsigned char* __restrict__ Abf8,
                                                   const unsigned char* __restrict__ WeT8,
                                                   const int* __restrict__ token_list,
                                                   const float* __restrict__ wA_s,
                                                   const float* __restrict__ wB_s,
                                                   const float* __restrict__ sA_s,
                                                   const int4* __restrict__ tile_desc,
                                                   const int* __restrict__ n_tiles,
                                                   float* __restrict__ out) {
    int b = blockIdx.x;
    int x8 = b & 7;
    int k = b >> 3;
    int colblk = ((x8 >> 1) << 1) + (k & 1);
    int tile = ((k >> 1) << 1) + (x8 & 1);
    if (tile >= *n_tiles) return;
    int4 dsc = tile_desc[tile];
    int loff = dsc.x, rows = dsc.y, ea = dsc.z, ebx = dsc.w;
    int ncol0 = colblk * NT;

    __shared__ __align__(16) unsigned char lds[2 * BUF_B];  // 24 KB: [buf][A 4K | B 8K]
    __shared__ int tokOut[MT];
    __shared__ int tokStage[MT];
    __shared__ float c1sh[MT], c2sh[MT];

    int t = threadIdx.x;
    int wave = t >> 6, lane = t & 63;

    if (t < MT) {
        int idx = loff + ((t < rows) ? t : 0);
        int tk = token_list[idx];
        tokStage[t] = tk;
        tokOut[t] = (t < rows) ? tk : -1;
        float s = sA_s[idx] * SB_F;
        c1sh[t] = s * wA_s[idx];
        c2sh[t] = s * wB_s[idx];
    }
    __syncthreads();

    const unsigned char* wbase = WeT8 + ((size_t)ea << 20);
    size_t ebd = ((size_t)(ebx - ea)) << 20;
    int l15 = lane & 15, hi = lane >> 4, q4 = hi * 4;

    const unsigned char* asrc;
    {
        int row = t >> 2;
        int lc = (t & 3) ^ ((row >> 1) & 3);
        asrc = Abf8 + (size_t)tokStage[row] * D_ + lc * 16;
    }
    const unsigned char* bsrc[2];
    #pragma unroll
    for (int i = 0; i < 2; i++) {
        int c = i * 256 + t;
        int row = c >> 2;
        int lc = (c & 3) ^ ((row >> 1) & 3);
        bsrc[i] = wbase + (size_t)(ncol0 + row) * D_ + lc * 16;
    }

    auto stage = [&](int ks, int buf) {
        int kb = (ks & 15) * 64;
        size_t bo = (size_t)kb + ((ks < 16) ? 0 : ebd);
        unsigned char* base = &lds[buf * BUF_B];
        gload16(asrc + kb, base + wave * 1024);
        #pragma unroll
        for (int i = 0; i < 2; i++)
            gload16(bsrc[i] + bo, base + 4096 + (i * 256 + wave * 64) * 16);
    };

    int wm = (wave >> 1) * 32, wn = (wave & 1) * 64;
    int aoff[2], boff[4];
    #pragma unroll
    for (int m = 0; m < 2; m++) {
        int r = wm + m * 16 + l15;
        aoff[m] = r * 64 + ((hi ^ ((r >> 1) & 3)) << 4);
    }
    #pragma unroll
    for (int n = 0; n < 4; n++) {
        int rb = wn + n * 16 + l15;
        boff[n] = 4096 + rb * 64 + ((hi ^ ((rb >> 1) & 3)) << 4);
    }

    i32x4 acc[2][4];
    unsigned pk[2][4][2];
    #pragma unroll
    for (int m = 0; m < 2; m++)
        #pragma unroll
        for (int n = 0; n < 4; n++) acc[m][n] = (i32x4){0, 0, 0, 0};

    stage(0, 0);
    for (int ks = 0; ks < KSTEPS; ++ks) {
        if (ks < KSTEPS - 1) {
            stage(ks + 1, (ks + 1) & 1);
            asm volatile("s_waitcnt vmcnt(3)" ::: "memory");
        } else {
            asm volatile("s_waitcnt vmcnt(0)" ::: "memory");
        }
        __builtin_amdgcn_s_barrier();
        if (ks == 16) {
            #pragma unroll
            for (int m = 0; m < 2; m++) {
                #pragma unroll
                for (int n = 0; n < 4; n++) {
                    float f0 = (float)acc[m][n][0] * c1sh[wm + m * 16 + q4 + 0];
                    float f1 = (float)acc[m][n][1] * c1sh[wm + m * 16 + q4 + 1];
                    float f2 = (float)acc[m][n][2] * c1sh[wm + m * 16 + q4 + 2];
                    float f3 = (float)acc[m][n][3] * c1sh[wm + m * 16 + q4 + 3];
                    pk[m][n][0] = (unsigned)f2b(f0) | ((unsigned)f2b(f1) << 16);
                    pk[m][n][1] = (unsigned)f2b(f2) | ((unsigned)f2b(f3) << 16);
                    acc[m][n] = (i32x4){0, 0, 0, 0};
                }
            }
        }
        const unsigned char* Ab = &lds[(ks & 1) * BUF_B];
        i32x4 a[2], bfr[4];
        #pragma unroll
        for (int m = 0; m < 2; m++)
            a[m] = *reinterpret_cast<const i32x4*>(&Ab[aoff[m]]);
        #pragma unroll
        for (int n = 0; n < 4; n++)
            bfr[n] = *reinterpret_cast<const i32x4*>(&Ab[boff[n]]);
        #pragma unroll
        for (int m = 0; m < 2; m++)
            #pragma unroll
            for (int n = 0; n < 4; n++)
                acc[m][n] = __builtin_amdgcn_mfma_i32_16x16x64_i8(a[m], bfr[n], acc[m][n], 0, 0, 0);
        __builtin_amdgcn_s_barrier();
    }

    #pragma unroll
    for (int m = 0; m < 2; m++) {
        #pragma unroll
        for (int n = 0; n < 4; n++) {
            int col = ncol0 + wn + n * 16 + l15;
            #pragma unroll
            for (int j = 0; j < 4; j++) {
                int r = wm + m * 16 + q4 + j;
                int tk = tokOut[r];
                unsigned u = pk[m][n][j >> 1];
                float part = __uint_as_float((j & 1) ? (u & 0xffff0000u) : (u << 16));
                if (tk >= 0) out[(size_t)tk * D_ + col] = part + (float)acc[m][n][j] * c2sh[r];
            }
        }
    }
}

extern "C" void kernel_launch(void* const* d_in, const int* in_sizes, int n_in,
                              void* d_out, int out_size, void* d_ws, size_t ws_size,
                              hipStream_t stream) {
    const float* x  = (const float*)d_in[0];
    const float* Wg = (const float*)d_in[1];
    const float* We = (const float*)d_in[2];
    float* out = (float*)d_out;

    size_t off = 0;
    auto alloc = [&](size_t bytes) -> void* {
        void* p = (char*)d_ws + off;
        off += (bytes + 255) & ~(size_t)255;
        return p;
    };
    unsigned char* WeT8 = (unsigned char*)alloc((size_t)E_ * 1024 * 1024);  // 8 MB
    unsigned char* Abf8 = (unsigned char*)alloc((size_t)NTOK * D_);         // 8.4 MB
    int*   g_tok      = (int*)  alloc(NTOK * 4);
    float* wA_tok     = (float*)alloc(NTOK * 4);
    float* wB_tok     = (float*)alloc(NTOK * 4);
    float* sA_tok     = (float*)alloc(NTOK * 4);
    int*   token_list = (int*)  alloc(NTOK * 4);
    float* wA_s       = (float*)alloc(NTOK * 4);
    float* wB_s       = (float*)alloc(NTOK * 4);
    float* sA_s       = (float*)alloc(NTOK * 4);
    int4*  tile_desc  = (int4*) alloc(MAX_TILES * 16);
    int*   n_tiles    = (int*)  alloc(4);

    prep_kernel<<<1024 + 2048, 256, 0, stream>>>(We, WeT8, x, Wg, g_tok, wA_tok, wB_tok,
                                                 sA_tok, Abf8);
    route_kernel<<<64, 256, 0, stream>>>(g_tok, wA_tok, wB_tok, sA_tok,
                                         token_list, wA_s, wB_s, sA_s, tile_desc, n_tiles);
    moe_gemm<<<8 * MAX_TILES, 256, 0, stream>>>(Abf8, WeT8, token_list, wA_s, wB_s, sA_s,
                                                tile_desc, n_tiles, out);
}

// Round 21
// 67.566 us; speedup vs baseline: 1.1718x; 1.1056x over previous
//
#include <hip/hip_runtime.h>
#include <hip/hip_bf16.h>
#include <stdint.h>

#define NTOK 8192
#define D_   1024
#define E_   8
#define MT   64
#define NT   128
#define KSTEPS 16     // 8 per expert half, BK=128 bytes
#define MAX_TILES 320
#define BUF_B 24576   // bytes per LDS buffer: A 64*128 + B 128*128

#define LIM_F  0.05412658773652741f      // sqrt(6/(D+D)) exact from shapes
#define SB_F   (LIM_F / 127.0f)
#define INVSB_F (127.0f / LIM_F)

typedef __attribute__((ext_vector_type(4))) int i32x4;

__device__ inline unsigned short f2b(float f) {
    unsigned int u = __float_as_uint(f);
    unsigned int r = (u + 0x7fffu + ((u >> 16) & 1u)) >> 16;
    return (unsigned short)r;
}
__device__ inline int q8(float v, float inv) {
    int q = __float2int_rn(v * inv);
    return max(-127, min(127, q));
}

// async global->LDS, 16B per lane; LDS dest = wave-uniform base + lane*16.
__device__ inline void gload16(const void* g, void* l) {
    __builtin_amdgcn_global_load_lds(
        (const __attribute__((address_space(1))) unsigned int*)(uintptr_t)g,
        (__attribute__((address_space(3))) unsigned int*)(unsigned int)(uintptr_t)l,
        16, 0, 0);
}

// ---- Phase 0+1 fused: gating + i8 cast (blocks 0..1023, R18 form) || We transpose+quant (1024..3071) ----
__global__ __launch_bounds__(256) void prep_kernel(const float* __restrict__ We,
                                                   unsigned char* __restrict__ WeT8,
                                                   const float* __restrict__ x,
                                                   const float* __restrict__ Wg,
                                                   int* __restrict__ g_tok,
                                                   float* __restrict__ wA_tok,
                                                   float* __restrict__ wB_tok,
                                                   float* __restrict__ sA_tok,
                                                   unsigned char* __restrict__ Abf8) {
    __shared__ __align__(16) float smem[8192];   // overlay: 8x1024 wgt | 64x65 tile
    int b = blockIdx.x;
    int t = threadIdx.x;
    if (b < 1024) {
        // ---- gating + per-token amax + i8 cast; 8 tokens/block, 2 per wave ----
        float* wgt = smem;   // transposed: wgt[e*1024 + d]
        for (int i = t; i < 8192; i += 256) wgt[(i & 7) * 1024 + (i >> 3)] = Wg[i];
        __syncthreads();
        int wave = t >> 6, lane = t & 63;
        int tok0 = b * 8 + wave * 2;

        for (int tki = 0; tki < 2; tki++) {
            int tok = tok0 + tki;
            const float* xr = x + (size_t)tok * D_;

            float4 xv[4];
            float acc[8] = {0.f, 0.f, 0.f, 0.f, 0.f, 0.f, 0.f, 0.f};
            float ax = 0.f;
            #pragma unroll
            for (int i = 0; i < 4; i++) {
                int d0 = i * 256 + lane * 4;
                xv[i] = *reinterpret_cast<const float4*>(xr + d0);
                ax = fmaxf(ax, fmaxf(fmaxf(fabsf(xv[i].x), fabsf(xv[i].y)),
                                     fmaxf(fabsf(xv[i].z), fabsf(xv[i].w))));
                #pragma unroll
                for (int e = 0; e < 8; e++) {
                    float4 w = *reinterpret_cast<const float4*>(&wgt[e * 1024 + d0]);
                    acc[e] += xv[i].x * w.x + xv[i].y * w.y + xv[i].z * w.z + xv[i].w * w.w;
                }
            }
            #pragma unroll
            for (int off = 32; off > 0; off >>= 1) ax = fmaxf(ax, __shfl_xor(ax, off, 64));
            #pragma unroll
            for (int e = 0; e < 8; e++)
                #pragma unroll
                for (int off = 32; off > 0; off >>= 1)
                    acc[e] += __shfl_xor(acc[e], off, 64);

            float best = acc[0]; int bi = 0;
            #pragma unroll
            for (int e = 1; e < 8; e++) { if (acc[e] > best) { best = acc[e]; bi = e; } }
            float second = -3.4e38f; int si = 0;
            #pragma unroll
            for (int e = 0; e < 8; e++) { if (e != bi && acc[e] > second) { second = acc[e]; si = e; } }
            float eb = __expf(second - best);
            eb = fmaxf(eb, 1e-20f);
            float w0 = 1.f / (1.f + eb);
            float w1 = eb / (1.f + eb);
            int ea, ebx; float wA, wB;
            if (bi < si) { ea = bi; ebx = si; wA = w0; wB = w1; }
            else         { ea = si; ebx = bi; wA = w1; wB = w0; }
            float inv = (ax > 0.f) ? 127.f / ax : 0.f;
            if (lane == 0) {
                g_tok[tok] = ea * 8 + ebx;
                wA_tok[tok] = wA;
                wB_tok[tok] = wB;
                sA_tok[tok] = ax / 127.f;
            }

            unsigned char* rowp = Abf8 + (size_t)tok * D_;
            #pragma unroll
            for (int i = 0; i < 4; i++) {
                int d0 = i * 256 + lane * 4;
                int q0 = q8(xv[i].x, inv), q1 = q8(xv[i].y, inv);
                int q2 = q8(xv[i].z, inv), q3 = q8(xv[i].w, inv);
                unsigned p = (q0 & 0xff) | ((q1 & 0xff) << 8) | ((q2 & 0xff) << 16) | ((q3 & 0xff) << 24);
                *reinterpret_cast<unsigned*>(rowp + d0) = p;
            }
        }
    } else {
        // ---- We (E,D,D) f32 -> WeT8 (E,M,D) int8, constant scale SB ----
        float (*tile)[65] = reinterpret_cast<float (*)[65]>(smem);
        int bb = b - 1024;
        int e = bb >> 8, rem = bb & 255;
        int m0 = (rem & 15) * 64, d0 = (rem >> 4) * 64;
        const float* src = We + ((size_t)e << 20);
        int r = t >> 4, c4 = (t & 15) * 4;
        #pragma unroll
        for (int i = 0; i < 4; i++) {
            int d = r + i * 16;
            float4 v = *reinterpret_cast<const float4*>(src + (size_t)(d0 + d) * D_ + m0 + c4);
            tile[d][c4 + 0] = v.x; tile[d][c4 + 1] = v.y;
            tile[d][c4 + 2] = v.z; tile[d][c4 + 3] = v.w;
        }
        __syncthreads();
        int m = t >> 2, dq = (t & 3) * 16;
        unsigned pk[4];
        #pragma unroll
        for (int jq = 0; jq < 4; jq++) {
            int q0 = q8(tile[dq + jq * 4 + 0][m], INVSB_F);
            int q1 = q8(tile[dq + jq * 4 + 1][m], INVSB_F);
            int q2 = q8(tile[dq + jq * 4 + 2][m], INVSB_F);
            int q3 = q8(tile[dq + jq * 4 + 3][m], INVSB_F);
            pk[jq] = (q0 & 0xff) | ((q1 & 0xff) << 8) | ((q2 & 0xff) << 16) | ((q3 & 0xff) << 24);
        }
        *reinterpret_cast<uint4*>(WeT8 + ((size_t)e << 20) + (size_t)(m0 + m) * D_ + d0 + dq) =
            make_uint4(pk[0], pk[1], pk[2], pk[3]);
    }
}

// ---------------- Phase 2: routing — 64 parallel blocks, uniform 64-row tiles ----------------
__global__ __launch_bounds__(256) void route_kernel(const int* __restrict__ g_tok,
                                                    const float* __restrict__ wA_tok,
                                                    const float* __restrict__ wB_tok,
                                                    const float* __restrict__ sA_tok,
                                                    int* __restrict__ token_list,
                                                    float* __restrict__ wA_s,
                                                    float* __restrict__ wB_s,
                                                    float* __restrict__ sA_s,
                                                    int4* __restrict__ tile_desc,
                                                    int* __restrict__ n_tiles_out) {
    int g = blockIdx.x;    // 0..63
    int t = threadIdx.x;   // 0..255
    __shared__ int cnt[64];
    __shared__ int pfx[256];
    __shared__ int startg, tbase, tottiles;
    if (t < 64) cnt[t] = 0;
    __syncthreads();

    int base = t * 32;
    int gl[32];
    int my = 0;
    #pragma unroll
    for (int k = 0; k < 32; k++) {
        gl[k] = g_tok[base + k];
        my += (gl[k] == g);
    }
    #pragma unroll
    for (int k = 0; k < 32; k++) atomicAdd(&cnt[gl[k]], 1);
    pfx[t] = my;
    __syncthreads();

    if (t == 0) {
        int run = 0, tb = 0, tt = 0;
        for (int gg = 0; gg < 64; gg++) {
            int c = cnt[gg];
            int n = (c + MT - 1) / MT;
            if (gg < g) { run += c; tb += n; }
            tt += n;
        }
        startg = run; tbase = tb; tottiles = tt;
    }
    for (int off = 1; off < 256; off <<= 1) {
        int add = (t >= off) ? pfx[t - off] : 0;
        __syncthreads();
        pfx[t] += add;
        __syncthreads();
    }

    int pos = startg + pfx[t] - my;
    #pragma unroll
    for (int k = 0; k < 32; k++) {
        if (gl[k] == g) {
            int idx = base + k;
            token_list[pos] = idx;
            wA_s[pos] = wA_tok[idx];
            wB_s[pos] = wB_tok[idx];
            sA_s[pos] = sA_tok[idx];
            pos++;
        }
    }
    if (t == 0) {
        int rem = cnt[g], off2 = 0, ti = tbase;
        while (rem > 0) {
            int take = (rem < MT) ? rem : MT;
            tile_desc[ti++] = make_int4(startg + off2, take, g >> 3, g & 7);
            off2 += take; rem -= take;
        }
        if (g == 0) *n_tiles_out = tottiles;
    }
}

// ---------------- Phase 3: grouped GEMM — int8, BK=128 (16 steps), 2-D XCD affinity ----------------
// 1-D grid b = x8 + 8k, x8 = XCD = 2*colpair + tileparity:
//   colblk = 2*(x8>>1) + (k&1), tile = 2*(k>>1) + (x8&1).   (R20-verified: FETCH 70->38 MB)
// BK=128 bytes halves step count -> per-step fixed cost (2 barriers + waitcnt) amortizes 2x.
// Swizzle: 128B rows = 8 slots of 16B; phys slot = logical ^ (row&7); read slot = hi + 4*ksub.
// ks 0..7: expert ea (i32 acc -> bf16-packed f32 partial at switch); ks 8..15: expert ebx.
__global__ __launch_bounds__(256, 3) void moe_gemm(const unsigned char* __restrict__ Abf8,
                                                   const unsigned char* __restrict__ WeT8,
                                                   const int* __restrict__ token_list,
                                                   const float* __restrict__ wA_s,
                                                   const float* __restrict__ wB_s,
                                                   const float* __restrict__ sA_s,
                                                   const int4* __restrict__ tile_desc,
                                                   const int* __restrict__ n_tiles,
                                                   float* __restrict__ out) {
    int b = blockIdx.x;
    int x8 = b & 7;
    int k = b >> 3;
    int colblk = ((x8 >> 1) << 1) + (k & 1);
    int tile = ((k >> 1) << 1) + (x8 & 1);
    if (tile >= *n_tiles) return;
    int4 dsc = tile_desc[tile];
    int loff = dsc.x, rows = dsc.y, ea = dsc.z, ebx = dsc.w;
    int ncol0 = colblk * NT;

    __shared__ __align__(16) unsigned char lds[2 * BUF_B];  // 48 KB: [buf][A 8K | B 16K]
    __shared__ int tokOut[MT];
    __shared__ int tokStage[MT];
    __shared__ float c1sh[MT], c2sh[MT];

    int t = threadIdx.x;
    int wave = t >> 6, lane = t & 63;

    if (t < MT) {
        int idx = loff + ((t < rows) ? t : 0);
        int tk = token_list[idx];
        tokStage[t] = tk;
        tokOut[t] = (t < rows) ? tk : -1;
        float s = sA_s[idx] * SB_F;
        c1sh[t] = s * wA_s[idx];
        c2sh[t] = s * wB_s[idx];
    }
    __syncthreads();

    const unsigned char* wbase = WeT8 + ((size_t)ea << 20);
    size_t ebd = ((size_t)(ebx - ea)) << 20;
    int l15 = lane & 15, hi = lane >> 4, q4 = hi * 4;

    // ---- staging roles: 16B chunks; row has 8 slots; phys slot s holds logical s^(row&7) ----
    // A: 512 chunks (64 rows x 8 slots), 2 gloads/thread; B: 1024 chunks, 4 gloads/thread.
    const unsigned char* asrc[2];
    #pragma unroll
    for (int i = 0; i < 2; i++) {
        int c = i * 256 + t;
        int row = c >> 3;
        int lc = (c & 7) ^ (row & 7);
        asrc[i] = Abf8 + (size_t)tokStage[row] * D_ + lc * 16;
    }
    const unsigned char* bsrc[4];
    #pragma unroll
    for (int i = 0; i < 4; i++) {
        int c = i * 256 + t;
        int row = c >> 3;
        int lc = (c & 7) ^ (row & 7);
        bsrc[i] = wbase + (size_t)(ncol0 + row) * D_ + lc * 16;
    }

    auto stage = [&](int ks, int buf) {
        int kb = (ks & 7) * 128;
        size_t bo = (size_t)kb + ((ks < 8) ? 0 : ebd);
        unsigned char* base = &lds[buf * BUF_B];
        #pragma unroll
        for (int i = 0; i < 2; i++)
            gload16(asrc[i] + kb, base + i * 4096 + wave * 1024);
        #pragma unroll
        for (int i = 0; i < 4; i++)
            gload16(bsrc[i] + bo, base + 8192 + i * 4096 + wave * 1024);
    };

    // ---- compute roles: wave grid 2(M)x2(N); wave-tile 32x64 ----
    int wm = (wave >> 1) * 32, wn = (wave & 1) * 64;
    int aoff[2][2], boff[2][4];
    #pragma unroll
    for (int ksub = 0; ksub < 2; ksub++) {
        #pragma unroll
        for (int m = 0; m < 2; m++) {
            int r = wm + m * 16 + l15;
            aoff[ksub][m] = r * 128 + (((hi + 4 * ksub) ^ (r & 7)) << 4);
        }
        #pragma unroll
        for (int n = 0; n < 4; n++) {
            int rb = wn + n * 16 + l15;
            boff[ksub][n] = 8192 + rb * 128 + (((hi + 4 * ksub) ^ (rb & 7)) << 4);
        }
    }

    i32x4 acc[2][4];
    unsigned pk[2][4][2];
    #pragma unroll
    for (int m = 0; m < 2; m++)
        #pragma unroll
        for (int n = 0; n < 4; n++) acc[m][n] = (i32x4){0, 0, 0, 0};

    stage(0, 0);
    for (int ks = 0; ks < KSTEPS; ++ks) {
        if (ks < KSTEPS - 1) {
            stage(ks + 1, (ks + 1) & 1);
            asm volatile("s_waitcnt vmcnt(6)" ::: "memory");
        } else {
            asm volatile("s_waitcnt vmcnt(0)" ::: "memory");
        }
        __builtin_amdgcn_s_barrier();
        if (ks == 8) {
            // expert switch: pack f32 partial (accA * c1[row]) as bf16 pairs, re-zero acc
            #pragma unroll
            for (int m = 0; m < 2; m++) {
                #pragma unroll
                for (int n = 0; n < 4; n++) {
                    float f0 = (float)acc[m][n][0] * c1sh[wm + m * 16 + q4 + 0];
                    float f1 = (float)acc[m][n][1] * c1sh[wm + m * 16 + q4 + 1];
                    float f2 = (float)acc[m][n][2] * c1sh[wm + m * 16 + q4 + 2];
                    float f3 = (float)acc[m][n][3] * c1sh[wm + m * 16 + q4 + 3];
                    pk[m][n][0] = (unsigned)f2b(f0) | ((unsigned)f2b(f1) << 16);
                    pk[m][n][1] = (unsigned)f2b(f2) | ((unsigned)f2b(f3) << 16);
                    acc[m][n] = (i32x4){0, 0, 0, 0};
                }
            }
        }
        const unsigned char* Ab = &lds[(ks & 1) * BUF_B];
        #pragma unroll
        for (int ksub = 0; ksub < 2; ++ksub) {
            i32x4 a[2], bfr[4];
            #pragma unroll
            for (int m = 0; m < 2; m++)
                a[m] = *reinterpret_cast<const i32x4*>(&Ab[aoff[ksub][m]]);
            #pragma unroll
            for (int n = 0; n < 4; n++)
                bfr[n] = *reinterpret_cast<const i32x4*>(&Ab[boff[ksub][n]]);
            #pragma unroll
            for (int m = 0; m < 2; m++)
                #pragma unroll
                for (int n = 0; n < 4; n++)
                    acc[m][n] = __builtin_amdgcn_mfma_i32_16x16x64_i8(a[m], bfr[n], acc[m][n], 0, 0, 0);
        }
        __builtin_amdgcn_s_barrier();   // readers done before next stage overwrites other buffer
    }

    // epilogue: single writer per out element; out = partial + accB * c2[row]
    #pragma unroll
    for (int m = 0; m < 2; m++) {
        #pragma unroll
        for (int n = 0; n < 4; n++) {
            int col = ncol0 + wn + n * 16 + l15;
            #pragma unroll
            for (int j = 0; j < 4; j++) {
                int r = wm + m * 16 + q4 + j;
                int tk = tokOut[r];
                unsigned u = pk[m][n][j >> 1];
                float part = __uint_as_float((j & 1) ? (u & 0xffff0000u) : (u << 16));
                if (tk >= 0) out[(size_t)tk * D_ + col] = part + (float)acc[m][n][j] * c2sh[r];
            }
        }
    }
}

extern "C" void kernel_launch(void* const* d_in, const int* in_sizes, int n_in,
                              void* d_out, int out_size, void* d_ws, size_t ws_size,
                              hipStream_t stream) {
    const float* x  = (const float*)d_in[0];
    const float* Wg = (const float*)d_in[1];
    const float* We = (const float*)d_in[2];
    float* out = (float*)d_out;

    size_t off = 0;
    auto alloc = [&](size_t bytes) -> void* {
        void* p = (char*)d_ws + off;
        off += (bytes + 255) & ~(size_t)255;
        return p;
    };
    unsigned char* WeT8 = (unsigned char*)alloc((size_t)E_ * 1024 * 1024);  // 8 MB
    unsigned char* Abf8 = (unsigned char*)alloc((size_t)NTOK * D_);         // 8.4 MB
    int*   g_tok      = (int*)  alloc(NTOK * 4);
    float* wA_tok     = (float*)alloc(NTOK * 4);
    float* wB_tok     = (float*)alloc(NTOK * 4);
    float* sA_tok     = (float*)alloc(NTOK * 4);
    int*   token_list = (int*)  alloc(NTOK * 4);
    float* wA_s       = (float*)alloc(NTOK * 4);
    float* wB_s       = (float*)alloc(NTOK * 4);
    float* sA_s       = (float*)alloc(NTOK * 4);
    int4*  tile_desc  = (int4*) alloc(MAX_TILES * 16);
    int*   n_tiles    = (int*)  alloc(4);

    prep_kernel<<<1024 + 2048, 256, 0, stream>>>(We, WeT8, x, Wg, g_tok, wA_tok, wB_tok,
                                                 sA_tok, Abf8);
    route_kernel<<<64, 256, 0, stream>>>(g_tok, wA_tok, wB_tok, sA_tok,
                                         token_list, wA_s, wB_s, sA_s, tile_desc, n_tiles);
    moe_gemm<<<8 * MAX_TILES, 256, 0, stream>>>(Abf8, WeT8, token_list, wA_s, wB_s, sA_s,
                                                tile_desc, n_tiles, out);
}